// Round 2
// 3425.602 us; speedup vs baseline: 1.1313x; 1.1313x over previous
//
#include <hip/hip_runtime.h>

// GPT-2 small forward on MI355X. bf16 MFMA GEMMs (fp32 accum), fp32 residual
// stream + LayerNorms. Dense GEMMs use m97-style 128x128 tiles with
// global_load_lds width-16 staging. Attention is a fused flash kernel
// (QK^T -> online softmax -> PV, S never materialized).

#define CN    768
#define NKV   2304
#define FCN   3072
#define TN    1024
#define BN    4
#define HN    12
#define NL    12
#define MTOT  4096   // B*T

typedef __attribute__((ext_vector_type(4))) float f32x4;
typedef __attribute__((ext_vector_type(8))) short short8;

typedef const __attribute__((address_space(1))) void* gas_t;
typedef __attribute__((address_space(3))) void* las_t;

__device__ __forceinline__ unsigned short f2b(float f) {
    unsigned int u = __float_as_uint(f);
    u += 0x7fffu + ((u >> 16) & 1u);          // RNE
    return (unsigned short)(u >> 16);
}
__device__ __forceinline__ float b2f(unsigned short h) {
    return __uint_as_float(((unsigned int)h) << 16);
}

// ---------------- 128x128 bf16 MFMA core (BK=32, global_load_lds) ----------
// A [M,K] bf16 row-major lda; B [N,K] bf16 row-major ldb (i.e. W^T layout).
// 256 threads = 4 waves in 2x2; wave covers 64x64 via 4x4 16x16x32 frags.
// LDS unpadded [128][32] (required: global_load_lds dest = wave base+lane*16).
__device__ __forceinline__ void gemm128(
        const unsigned short* __restrict__ A, int lda,
        const unsigned short* __restrict__ B, int ldb,
        int m0, int n0, int kbeg, int kend, f32x4 acc[4][4])
{
    __shared__ __align__(16) unsigned short As[128 * 32];
    __shared__ __align__(16) unsigned short Bs[128 * 32];
    const int tid  = threadIdx.x;
    const int wave = tid >> 6;
    const int lane = tid & 63;
    const int quad = lane >> 4;
    const int l16  = lane & 15;
    const int wm   = (wave & 1) * 64;
    const int wn   = (wave >> 1) * 64;
    // staging: chunk it in {0,1}: row = it*64 + wave*16 + lane/4, col8=(lane&3)*8
    const int srow = wave * 16 + (lane >> 2);
    const int scol = (lane & 3) << 3;
    const unsigned short* ag = A + (long)(m0 + srow) * lda + scol;
    const unsigned short* bg = B + (long)(n0 + srow) * ldb + scol;
    unsigned short* asw = As + wave * 512;      // +lane*8 implicit in HW
    unsigned short* bsw = Bs + wave * 512;

    for (int k0 = kbeg; k0 < kend; k0 += 32) {
        __syncthreads();                        // WAR vs prior frag reads
        __builtin_amdgcn_global_load_lds((gas_t)(ag + k0),                  (las_t)(asw),            16, 0, 0);
        __builtin_amdgcn_global_load_lds((gas_t)(ag + k0 + (long)64 * lda), (las_t)(asw + 64 * 32),  16, 0, 0);
        __builtin_amdgcn_global_load_lds((gas_t)(bg + k0),                  (las_t)(bsw),            16, 0, 0);
        __builtin_amdgcn_global_load_lds((gas_t)(bg + k0 + (long)64 * ldb), (las_t)(bsw + 64 * 32),  16, 0, 0);
        __syncthreads();                        // compiler adds vmcnt(0) drain
        short8 af[4], bf[4];
#pragma unroll
        for (int i = 0; i < 4; ++i)
            af[i] = *(const short8*)(As + (wm + i * 16 + l16) * 32 + quad * 8);
#pragma unroll
        for (int j = 0; j < 4; ++j)
            bf[j] = *(const short8*)(Bs + (wn + j * 16 + l16) * 32 + quad * 8);
#pragma unroll
        for (int i = 0; i < 4; ++i)
#pragma unroll
            for (int j = 0; j < 4; ++j)
                acc[i][j] = __builtin_amdgcn_mfma_f32_16x16x32_bf16(af[i], bf[j], acc[i][j], 0, 0, 0);
    }
}
// C/D: value r of acc[i][j] -> row = m0+wm+i*16+quad*4+r, col = n0+wn+j*16+l16.

// ---------------- GEMM kernels ----------------
// QKV: [4096,768] @ W^T[2304,768] + bias -> split q/k [B,H,T,D], vT [B,H,D,T]
__global__ __launch_bounds__(256) void k_qkv128(
        const unsigned short* __restrict__ A, const unsigned short* __restrict__ B,
        const float* __restrict__ bias,
        unsigned short* __restrict__ qb, unsigned short* __restrict__ kb,
        unsigned short* __restrict__ vt)
{
    f32x4 acc[4][4];
#pragma unroll
    for (int i = 0; i < 4; ++i)
#pragma unroll
        for (int j = 0; j < 4; ++j) acc[i][j] = 0.f;
    const int m0 = blockIdx.x * 128, n0 = blockIdx.y * 128;
    gemm128(A, CN, B, CN, m0, n0, 0, CN, acc);
    const int wave = threadIdx.x >> 6, lane = threadIdx.x & 63;
    const int quad = lane >> 4, l16 = lane & 15;
    const int wm = (wave & 1) * 64, wn = (wave >> 1) * 64;
#pragma unroll
    for (int j = 0; j < 4; ++j) {
        int col = n0 + wn + j * 16 + l16;
        float bv = bias[col];
        int which = col / CN;
        int cc = col - which * CN;
        int h = cc >> 6, d = cc & 63;
#pragma unroll
        for (int i = 0; i < 4; ++i) {
#pragma unroll
            for (int r = 0; r < 4; ++r) {
                int row = m0 + wm + i * 16 + quad * 4 + r;
                int b = row >> 10, t = row & 1023;
                int bh = b * HN + h;
                unsigned short val = f2b(acc[i][j][r] + bv);
                if (which == 0)      qb[(bh * TN + t) * 64 + d] = val;
                else if (which == 1) kb[(bh * TN + t) * 64 + d] = val;
                else                 vt[(bh * 64 + d) * TN + t] = val;
            }
        }
    }
}

// FC: gelu(A@W^T + bias) -> bf16 [4096,3072]
__global__ __launch_bounds__(256) void k_fc128(
        const unsigned short* __restrict__ A, const unsigned short* __restrict__ B,
        const float* __restrict__ bias, unsigned short* __restrict__ G)
{
    f32x4 acc[4][4];
#pragma unroll
    for (int i = 0; i < 4; ++i)
#pragma unroll
        for (int j = 0; j < 4; ++j) acc[i][j] = 0.f;
    const int m0 = blockIdx.x * 128, n0 = blockIdx.y * 128;
    gemm128(A, CN, B, CN, m0, n0, 0, CN, acc);
    const int wave = threadIdx.x >> 6, lane = threadIdx.x & 63;
    const int quad = lane >> 4, l16 = lane & 15;
    const int wm = (wave & 1) * 64, wn = (wave >> 1) * 64;
#pragma unroll
    for (int j = 0; j < 4; ++j) {
        int col = n0 + wn + j * 16 + l16;
        float bv = bias[col];
#pragma unroll
        for (int i = 0; i < 4; ++i)
#pragma unroll
            for (int r = 0; r < 4; ++r) {
                int row = m0 + wm + i * 16 + quad * 4 + r;
                float u = acc[i][j][r] + bv;
                float c = 0.7978845608028654f * (u + 0.044715f * u * u * u);
                float g = 0.5f * u * (1.0f + tanhf(c));
                G[(long)row * FCN + col] = f2b(g);
            }
    }
}

// Residual GEMM with split-K: X += A@W^T (+bias on kz==0), fp32 atomics.
__global__ __launch_bounds__(256) void k_res128(
        const unsigned short* __restrict__ A, int lda,
        const unsigned short* __restrict__ B, int K, int ksplit,
        const float* __restrict__ bias, float* __restrict__ X)
{
    f32x4 acc[4][4];
#pragma unroll
    for (int i = 0; i < 4; ++i)
#pragma unroll
        for (int j = 0; j < 4; ++j) acc[i][j] = 0.f;
    const int m0 = blockIdx.x * 128, n0 = blockIdx.y * 128;
    const int kz = blockIdx.z;
    const int klen = K / ksplit;
    gemm128(A, lda, B, K, m0, n0, kz * klen, kz * klen + klen, acc);
    const int wave = threadIdx.x >> 6, lane = threadIdx.x & 63;
    const int quad = lane >> 4, l16 = lane & 15;
    const int wm = (wave & 1) * 64, wn = (wave >> 1) * 64;
#pragma unroll
    for (int j = 0; j < 4; ++j) {
        int col = n0 + wn + j * 16 + l16;
        float bv = (kz == 0) ? bias[col] : 0.f;
#pragma unroll
        for (int i = 0; i < 4; ++i)
#pragma unroll
            for (int r = 0; r < 4; ++r) {
                int row = m0 + wm + i * 16 + quad * 4 + r;
                atomicAdd(&X[(long)row * CN + col], acc[i][j][r] + bv);
            }
    }
}

// ---------------- fused flash attention ----------------
// grid (TN/128, 1, BN*HN), 256 threads = 4 waves. Each wave owns 32 q-rows
// of a 128-row Q block; KV tiles of 64. qb,kb: [BH][T][64]; vt: [BH][64][T].
// Online softmax in MFMA C-layout: row = quad*4+r (same mapping for S and Y
// accumulators -> rescale needs no cross-lane). Row reduce = shfl_xor 1,2,4,8
// (quad-preserving, 16-lane groups). P transposed to A-frag layout via a
// padded per-wave LDS buffer (stride 70 shorts, ~2-way banks both sides).
// K/V/Q LDS tiles are [rows][64] with slot XOR-swizzle (slot ^= row&7),
// applied on the pre-swizzled GLOBAL source (global_load_lds dest is linear)
// and on the ds_read side — breaks the 16-way conflict of stride-128B rows.
__global__ __launch_bounds__(256) void k_attn(
        const unsigned short* __restrict__ qb, const unsigned short* __restrict__ kb,
        const unsigned short* __restrict__ vt, unsigned short* __restrict__ y)
{
    __shared__ __align__(16) unsigned short Qs[128 * 64];
    __shared__ __align__(16) unsigned short Ks[64 * 64];
    __shared__ __align__(16) unsigned short Vs[64 * 64];
    __shared__ __align__(16) unsigned short Ps[4 * 32 * 70];

    const int tid  = threadIdx.x;
    const int wave = tid >> 6;
    const int lane = tid & 63;
    const int quad = lane >> 4;
    const int l16  = lane & 15;
    const int bm   = blockIdx.x;
    const int z    = blockIdx.z;

    const unsigned short* qg = qb + (long)z * TN * 64;
    const unsigned short* kg = kb + (long)z * TN * 64;
    const unsigned short* vg = vt + (long)z * 64 * TN;

    const int r8 = lane >> 3;          // row within an 8-row chunk (1KB)
    const int sl = lane & 7;           // 16B slot within a 128B row

    // ---- stage Q [128][64]: LDS[row][s] = Q[row][s ^ (row&7)] ----
#pragma unroll
    for (int c = 0; c < 4; ++c) {
        int chunk = wave * 4 + c;
        int row = chunk * 8 + r8;
        int slot = sl ^ (row & 7);
        __builtin_amdgcn_global_load_lds(
            (gas_t)(qg + (long)(bm * 128 + row) * 64 + slot * 8),
            (las_t)(Qs + chunk * 512), 16, 0, 0);
    }
    __syncthreads();

    // Q fragments in registers for the whole KV loop (wave-local rows)
    short8 qf[2][2];
#pragma unroll
    for (int i = 0; i < 2; ++i)
#pragma unroll
        for (int ks = 0; ks < 2; ++ks) {
            int row = wave * 32 + i * 16 + l16;
            int slot = (ks * 4 + quad) ^ (row & 7);
            qf[i][ks] = *(const short8*)(Qs + row * 64 + slot * 8);
        }

    f32x4 acc[2][4];
#pragma unroll
    for (int i = 0; i < 2; ++i)
#pragma unroll
        for (int j = 0; j < 4; ++j) acc[i][j] = 0.f;
    float m_run[2][4], l_run[2][4];
#pragma unroll
    for (int i = 0; i < 2; ++i)
#pragma unroll
        for (int r = 0; r < 4; ++r) { m_run[i][r] = -3e38f; l_run[i][r] = 0.f; }

    const int qbase = bm * 128 + wave * 32;
    const int nt = 2 * bm + 2;                 // causal: tiles k0=0..(bm*128+64)
    unsigned short* pw = Ps + wave * (32 * 70);

    for (int t = 0; t < nt; ++t) {
        const int k0 = t * 64;
        __syncthreads();                       // WAR on Ks/Vs
#pragma unroll
        for (int c = 0; c < 2; ++c) {
            int chunk = wave * 2 + c;
            int row = chunk * 8 + r8;
            int slot = sl ^ (row & 7);
            __builtin_amdgcn_global_load_lds(
                (gas_t)(kg + (long)(k0 + row) * 64 + slot * 8),
                (las_t)(Ks + chunk * 512), 16, 0, 0);
            __builtin_amdgcn_global_load_lds(
                (gas_t)(vg + (long)row * TN + k0 + slot * 8),
                (las_t)(Vs + chunk * 512), 16, 0, 0);
        }
        __syncthreads();                       // RAW (vmcnt(0) drain at barrier)

        // S = Q K^T  (A=Q rows q, B=K rows k, kd=d)
        f32x4 s[2][4];
#pragma unroll
        for (int i = 0; i < 2; ++i)
#pragma unroll
            for (int j = 0; j < 4; ++j) s[i][j] = 0.f;
#pragma unroll
        for (int j = 0; j < 4; ++j) {
            int row = j * 16 + l16;
#pragma unroll
            for (int ks = 0; ks < 2; ++ks) {
                int slot = (ks * 4 + quad) ^ (row & 7);
                short8 kf = *(const short8*)(Ks + row * 64 + slot * 8);
#pragma unroll
                for (int i = 0; i < 2; ++i)
                    s[i][j] = __builtin_amdgcn_mfma_f32_16x16x32_bf16(qf[i][ks], kf, s[i][j], 0, 0, 0);
            }
        }

        // online softmax per q-row (i,r). C-layout row = qbase+i*16+quad*4+r.
#pragma unroll
        for (int i = 0; i < 2; ++i) {
#pragma unroll
            for (int r = 0; r < 4; ++r) {
                const int qrow = qbase + i * 16 + quad * 4 + r;
                float mx = -3e38f;
#pragma unroll
                for (int j = 0; j < 4; ++j) {
                    float v = s[i][j][r] * 0.125f;
                    if (k0 + j * 16 + l16 > qrow) v = -3e38f;   // causal mask
                    s[i][j][r] = v;
                    mx = fmaxf(mx, v);
                }
#pragma unroll
                for (int o = 1; o < 16; o <<= 1) mx = fmaxf(mx, __shfl_xor(mx, o));
                const float mnew = fmaxf(m_run[i][r], mx);
                const float resc = __expf(m_run[i][r] - mnew);  // 0 on first tile
                m_run[i][r] = mnew;
                float ls = 0.f;
#pragma unroll
                for (int j = 0; j < 4; ++j) {
                    float p = __expf(s[i][j][r] - mnew);
                    s[i][j][r] = p;
                    ls += p;
                }
#pragma unroll
                for (int o = 1; o < 16; o <<= 1) ls += __shfl_xor(ls, o);
                l_run[i][r] = l_run[i][r] * resc + ls;
#pragma unroll
                for (int j = 0; j < 4; ++j)
                    acc[i][j][r] *= resc;       // same row mapping as S: no shfl
            }
        }

        // P -> per-wave LDS (bf16), C-layout write / A-frag read
#pragma unroll
        for (int i = 0; i < 2; ++i)
#pragma unroll
            for (int j = 0; j < 4; ++j)
#pragma unroll
                for (int r = 0; r < 4; ++r)
                    pw[(i * 16 + quad * 4 + r) * 70 + j * 16 + l16] = f2b(s[i][j][r]);
        __syncthreads();                       // orders P write->read (lgkm drain)

        short8 pa[2][2];
#pragma unroll
        for (int i = 0; i < 2; ++i)
#pragma unroll
            for (int ks = 0; ks < 2; ++ks)
                pa[i][ks] = *(const short8*)(pw + (i * 16 + l16) * 70 + ks * 32 + quad * 8);

        // Y += P V   (A=P rows q kd=k, B=V^T rows d kd=k from vt layout)
#pragma unroll
        for (int j = 0; j < 4; ++j) {
            int row = j * 16 + l16;
#pragma unroll
            for (int ks = 0; ks < 2; ++ks) {
                int slot = (ks * 4 + quad) ^ (row & 7);
                short8 vf = *(const short8*)(Vs + row * 64 + slot * 8);
#pragma unroll
                for (int i = 0; i < 2; ++i)
                    acc[i][j] = __builtin_amdgcn_mfma_f32_16x16x32_bf16(pa[i][ks], vf, acc[i][j], 0, 0, 0);
            }
        }
    }

    // epilogue: Y = acc / l, write [B,T,C] at col h*64
    const int b = z / HN, h = z - b * HN;
    unsigned short* yb = y + (long)b * TN * CN + h * 64;
#pragma unroll
    for (int i = 0; i < 2; ++i)
#pragma unroll
        for (int r = 0; r < 4; ++r) {
            const float inv = 1.0f / l_run[i][r];
            const int row = qbase + i * 16 + quad * 4 + r;
#pragma unroll
            for (int j = 0; j < 4; ++j)
                yb[(long)row * CN + j * 16 + l16] = f2b(acc[i][j][r] * inv);
        }
}

// ---------------- small kernels ----------------
__device__ __forceinline__ float blk_sum(float v, float* red) {
#pragma unroll
    for (int o = 32; o > 0; o >>= 1) v += __shfl_xor(v, o);
    if ((threadIdx.x & 63) == 0) red[threadIdx.x >> 6] = v;
    __syncthreads();
    v = red[0] + red[1] + red[2] + red[3];
    __syncthreads();
    return v;
}

__global__ __launch_bounds__(256) void k_ln(
        const float* __restrict__ X, const float* __restrict__ w,
        const float* __restrict__ b, unsigned short* __restrict__ O)
{
    __shared__ float red[4];
    const int row = blockIdx.x, tid = threadIdx.x;
    const float* xr = X + (long)row * CN;
    float v[3], s = 0.f, sq = 0.f;
#pragma unroll
    for (int i = 0; i < 3; ++i) {
        v[i] = xr[tid + i * 256];
        s += v[i]; sq += v[i] * v[i];
    }
    s  = blk_sum(s, red);
    sq = blk_sum(sq, red);
    const float mu = s * (1.0f / CN);
    const float var = sq * (1.0f / CN) - mu * mu;
    const float rstd = rsqrtf(var + 1e-5f);
    unsigned short* orow = O + (long)row * CN;
#pragma unroll
    for (int i = 0; i < 3; ++i) {
        int c = tid + i * 256;
        orow[c] = f2b((v[i] - mu) * rstd * w[c] + b[c]);
    }
}

// final LN + head dot (w_head [768,1]) -> out[row] fp32
__global__ __launch_bounds__(256) void k_final(
        const float* __restrict__ X, const float* __restrict__ w,
        const float* __restrict__ b, const float* __restrict__ wh,
        float* __restrict__ out)
{
    __shared__ float red[4];
    const int row = blockIdx.x, tid = threadIdx.x;
    const float* xr = X + (long)row * CN;
    float v[3], s = 0.f, sq = 0.f;
#pragma unroll
    for (int i = 0; i < 3; ++i) {
        v[i] = xr[tid + i * 256];
        s += v[i]; sq += v[i] * v[i];
    }
    s  = blk_sum(s, red);
    sq = blk_sum(sq, red);
    const float mu = s * (1.0f / CN);
    const float rstd = rsqrtf(sq * (1.0f / CN) - mu * mu + 1e-5f);
    float acc = 0.f;
#pragma unroll
    for (int i = 0; i < 3; ++i) {
        int c = tid + i * 256;
        acc += ((v[i] - mu) * rstd * w[c] + b[c]) * wh[c];
    }
    acc = blk_sum(acc, red);
    if (tid == 0) out[row] = acc;
}

// x = wte[idx] + wpe
__global__ __launch_bounds__(256) void k_embed(
        const int* __restrict__ idx, const float* __restrict__ wte,
        const float* __restrict__ wpe, float* __restrict__ X)
{
    long e = (long)blockIdx.x * 256 + threadIdx.x;
    int c = (int)(e % CN);
    int bt = (int)(e / CN);
    int t = bt & 1023;
    int tok = idx[bt];
    X[e] = wte[(long)tok * CN + c] + wpe[(long)t * CN + c];
}

// fp32 [K,N] -> bf16 [N,K] (per layer z), 32x32 LDS tile
__global__ __launch_bounds__(256) void k_transpose(
        const float* __restrict__ in, unsigned short* __restrict__ out, int K, int N)
{
    __shared__ float tile[32][33];
    const int z = blockIdx.z;
    in  += (long)z * K * N;
    out += (long)z * K * N;
    const int n0 = blockIdx.x * 32, k0 = blockIdx.y * 32;
    const int tx = threadIdx.x & 31, ty = threadIdx.x >> 5;
#pragma unroll
    for (int i = 0; i < 4; ++i)
        tile[ty + i * 8][tx] = in[(long)(k0 + ty + i * 8) * N + n0 + tx];
    __syncthreads();
#pragma unroll
    for (int i = 0; i < 4; ++i)
        out[(long)(n0 + ty + i * 8) * K + k0 + tx] = f2b(tile[tx][ty + i * 8]);
}

// ---------------- host ----------------
extern "C" void kernel_launch(void* const* d_in, const int* in_sizes, int n_in,
                              void* d_out, int out_size, void* d_ws, size_t ws_size,
                              hipStream_t stream)
{
    const int*   idx    = (const int*)  d_in[0];
    const float* wte    = (const float*)d_in[1];
    const float* wpe    = (const float*)d_in[2];
    const float* ln1_w  = (const float*)d_in[3];
    const float* ln1_b  = (const float*)d_in[4];
    const float* w_qkv  = (const float*)d_in[5];
    const float* b_qkv  = (const float*)d_in[6];
    const float* w_ao   = (const float*)d_in[7];
    const float* b_ao   = (const float*)d_in[8];
    const float* ln2_w  = (const float*)d_in[9];
    const float* ln2_b  = (const float*)d_in[10];
    const float* w_fc   = (const float*)d_in[11];
    const float* b_fc   = (const float*)d_in[12];
    const float* w_fp   = (const float*)d_in[13];
    const float* b_fp   = (const float*)d_in[14];
    const float* lnf_w  = (const float*)d_in[15];
    const float* lnf_b  = (const float*)d_in[16];
    const float* w_head = (const float*)d_in[17];
    float* out = (float*)d_out;

    char* ws = (char*)d_ws;
    unsigned short* wqkvT = (unsigned short*)(ws + 0L);
    unsigned short* waoT  = (unsigned short*)(ws + 42467328L);
    unsigned short* wfcT  = (unsigned short*)(ws + 56623104L);
    unsigned short* wfpT  = (unsigned short*)(ws + 113246208L);
    float*          x     = (float*)         (ws + 169869312L);
    unsigned short* hb    = (unsigned short*)(ws + 182452224L);
    unsigned short* qb    = (unsigned short*)(ws + 188743680L);
    unsigned short* kb    = (unsigned short*)(ws + 195035136L);
    unsigned short* vt    = (unsigned short*)(ws + 201326592L);
    unsigned short* y     = (unsigned short*)(ws + 308281344L);
    unsigned short* g     = (unsigned short*)(ws + 314572800L);

    hipLaunchKernelGGL(k_transpose, dim3(NKV / 32, CN / 32, NL), dim3(256), 0, stream,
                       w_qkv, wqkvT, CN, NKV);
    hipLaunchKernelGGL(k_transpose, dim3(CN / 32, CN / 32, NL), dim3(256), 0, stream,
                       w_ao, waoT, CN, CN);
    hipLaunchKernelGGL(k_transpose, dim3(FCN / 32, CN / 32, NL), dim3(256), 0, stream,
                       w_fc, wfcT, CN, FCN);
    hipLaunchKernelGGL(k_transpose, dim3(CN / 32, FCN / 32, NL), dim3(256), 0, stream,
                       w_fp, wfpT, FCN, CN);

    hipLaunchKernelGGL(k_embed, dim3(MTOT * CN / 256), dim3(256), 0, stream,
                       idx, wte, wpe, x);

    for (int l = 0; l < NL; ++l) {
        hipLaunchKernelGGL(k_ln, dim3(MTOT), dim3(256), 0, stream,
                           x, ln1_w + l * CN, ln1_b + l * CN, hb);
        hipLaunchKernelGGL(k_qkv128, dim3(MTOT / 128, NKV / 128), dim3(256), 0, stream,
                           hb, wqkvT + (long)l * NKV * CN, b_qkv + l * NKV, qb, kb, vt);
        hipLaunchKernelGGL(k_attn, dim3(TN / 128, 1, BN * HN), dim3(256), 0, stream,
                           qb, kb, vt, y);
        hipLaunchKernelGGL(k_res128, dim3(MTOT / 128, CN / 128, 2), dim3(256), 0, stream,
                           y, CN, waoT + (long)l * CN * CN, CN, 2, b_ao + l * CN, x);
        hipLaunchKernelGGL(k_ln, dim3(MTOT), dim3(256), 0, stream,
                           x, ln2_w + l * CN, ln2_b + l * CN, hb);
        hipLaunchKernelGGL(k_fc128, dim3(MTOT / 128, FCN / 128), dim3(256), 0, stream,
                           hb, wfcT + (long)l * FCN * CN, b_fc + l * FCN, g);
        hipLaunchKernelGGL(k_res128, dim3(MTOT / 128, CN / 128, 4), dim3(256), 0, stream,
                           g, FCN, wfpT + (long)l * FCN * CN, FCN, 4, b_fp + l * CN, x);
    }

    hipLaunchKernelGGL(k_final, dim3(MTOT), dim3(256), 0, stream,
                       x, lnf_w, lnf_b, w_head, out);
}

// Round 3
// 3239.185 us; speedup vs baseline: 1.1964x; 1.0576x over previous
//
#include <hip/hip_runtime.h>

// GPT-2 small forward on MI355X. bf16 MFMA GEMMs (fp32 accum), fp32 residual
// stream + LayerNorms. Dense GEMMs use m97-style 128x128 tiles with
// global_load_lds width-16 staging. Attention is a fused flash kernel
// (QK^T -> online softmax -> PV, S never materialized), with complementary
// q-block pairing (bm, 7-bm) per workgroup for deterministic load balance.

#define CN    768
#define NKV   2304
#define FCN   3072
#define TN    1024
#define BN    4
#define HN    12
#define NL    12
#define MTOT  4096   // B*T

typedef __attribute__((ext_vector_type(4))) float f32x4;
typedef __attribute__((ext_vector_type(8))) short short8;
typedef __attribute__((ext_vector_type(4))) unsigned short u16x4;

typedef const __attribute__((address_space(1))) void* gas_t;
typedef __attribute__((address_space(3))) void* las_t;

__device__ __forceinline__ unsigned short f2b(float f) {
    unsigned int u = __float_as_uint(f);
    u += 0x7fffu + ((u >> 16) & 1u);          // RNE
    return (unsigned short)(u >> 16);
}
__device__ __forceinline__ float b2f(unsigned short h) {
    return __uint_as_float(((unsigned int)h) << 16);
}

// ---------------- 128x128 bf16 MFMA core (BK=32, global_load_lds) ----------
// A [M,K] bf16 row-major lda; B [N,K] bf16 row-major ldb (i.e. W^T layout).
// 256 threads = 4 waves in 2x2; wave covers 64x64 via 4x4 16x16x32 frags.
// LDS unpadded [128][32] (required: global_load_lds dest = wave base+lane*16).
__device__ __forceinline__ void gemm128(
        const unsigned short* __restrict__ A, int lda,
        const unsigned short* __restrict__ B, int ldb,
        int m0, int n0, int kbeg, int kend, f32x4 acc[4][4])
{
    __shared__ __align__(16) unsigned short As[128 * 32];
    __shared__ __align__(16) unsigned short Bs[128 * 32];
    const int tid  = threadIdx.x;
    const int wave = tid >> 6;
    const int lane = tid & 63;
    const int quad = lane >> 4;
    const int l16  = lane & 15;
    const int wm   = (wave & 1) * 64;
    const int wn   = (wave >> 1) * 64;
    // staging: chunk it in {0,1}: row = it*64 + wave*16 + lane/4, col8=(lane&3)*8
    const int srow = wave * 16 + (lane >> 2);
    const int scol = (lane & 3) << 3;
    const unsigned short* ag = A + (long)(m0 + srow) * lda + scol;
    const unsigned short* bg = B + (long)(n0 + srow) * ldb + scol;
    unsigned short* asw = As + wave * 512;      // +lane*8 implicit in HW
    unsigned short* bsw = Bs + wave * 512;

    for (int k0 = kbeg; k0 < kend; k0 += 32) {
        __syncthreads();                        // WAR vs prior frag reads
        __builtin_amdgcn_global_load_lds((gas_t)(ag + k0),                  (las_t)(asw),            16, 0, 0);
        __builtin_amdgcn_global_load_lds((gas_t)(ag + k0 + (long)64 * lda), (las_t)(asw + 64 * 32),  16, 0, 0);
        __builtin_amdgcn_global_load_lds((gas_t)(bg + k0),                  (las_t)(bsw),            16, 0, 0);
        __builtin_amdgcn_global_load_lds((gas_t)(bg + k0 + (long)64 * ldb), (las_t)(bsw + 64 * 32),  16, 0, 0);
        __syncthreads();                        // compiler adds vmcnt(0) drain
        short8 af[4], bf[4];
#pragma unroll
        for (int i = 0; i < 4; ++i)
            af[i] = *(const short8*)(As + (wm + i * 16 + l16) * 32 + quad * 8);
#pragma unroll
        for (int j = 0; j < 4; ++j)
            bf[j] = *(const short8*)(Bs + (wn + j * 16 + l16) * 32 + quad * 8);
#pragma unroll
        for (int i = 0; i < 4; ++i)
#pragma unroll
            for (int j = 0; j < 4; ++j)
                acc[i][j] = __builtin_amdgcn_mfma_f32_16x16x32_bf16(af[i], bf[j], acc[i][j], 0, 0, 0);
    }
}
// C/D: value r of acc[i][j] -> row = m0+wm+i*16+quad*4+r, col = n0+wn+j*16+l16.

// ---------------- GEMM kernels ----------------
// QKV: [4096,768] @ W^T[2304,768] + bias -> split q/k [B,H,T,D], vT [B,H,D,T]
__global__ __launch_bounds__(256) void k_qkv128(
        const unsigned short* __restrict__ A, const unsigned short* __restrict__ B,
        const float* __restrict__ bias,
        unsigned short* __restrict__ qb, unsigned short* __restrict__ kb,
        unsigned short* __restrict__ vt)
{
    f32x4 acc[4][4];
#pragma unroll
    for (int i = 0; i < 4; ++i)
#pragma unroll
        for (int j = 0; j < 4; ++j) acc[i][j] = 0.f;
    const int m0 = blockIdx.x * 128, n0 = blockIdx.y * 128;
    gemm128(A, CN, B, CN, m0, n0, 0, CN, acc);
    const int wave = threadIdx.x >> 6, lane = threadIdx.x & 63;
    const int quad = lane >> 4, l16 = lane & 15;
    const int wm = (wave & 1) * 64, wn = (wave >> 1) * 64;
#pragma unroll
    for (int j = 0; j < 4; ++j) {
        int col = n0 + wn + j * 16 + l16;
        float bv = bias[col];
        int which = col / CN;
        int cc = col - which * CN;
        int h = cc >> 6, d = cc & 63;
#pragma unroll
        for (int i = 0; i < 4; ++i) {
#pragma unroll
            for (int r = 0; r < 4; ++r) {
                int row = m0 + wm + i * 16 + quad * 4 + r;
                int b = row >> 10, t = row & 1023;
                int bh = b * HN + h;
                unsigned short val = f2b(acc[i][j][r] + bv);
                if (which == 0)      qb[(bh * TN + t) * 64 + d] = val;
                else if (which == 1) kb[(bh * TN + t) * 64 + d] = val;
                else                 vt[(bh * 64 + d) * TN + t] = val;
            }
        }
    }
}

// FC: gelu(A@W^T + bias) -> bf16 [4096,3072]
__global__ __launch_bounds__(256) void k_fc128(
        const unsigned short* __restrict__ A, const unsigned short* __restrict__ B,
        const float* __restrict__ bias, unsigned short* __restrict__ G)
{
    f32x4 acc[4][4];
#pragma unroll
    for (int i = 0; i < 4; ++i)
#pragma unroll
        for (int j = 0; j < 4; ++j) acc[i][j] = 0.f;
    const int m0 = blockIdx.x * 128, n0 = blockIdx.y * 128;
    gemm128(A, CN, B, CN, m0, n0, 0, CN, acc);
    const int wave = threadIdx.x >> 6, lane = threadIdx.x & 63;
    const int quad = lane >> 4, l16 = lane & 15;
    const int wm = (wave & 1) * 64, wn = (wave >> 1) * 64;
#pragma unroll
    for (int j = 0; j < 4; ++j) {
        int col = n0 + wn + j * 16 + l16;
        float bv = bias[col];
#pragma unroll
        for (int i = 0; i < 4; ++i)
#pragma unroll
            for (int r = 0; r < 4; ++r) {
                int row = m0 + wm + i * 16 + quad * 4 + r;
                float u = acc[i][j][r] + bv;
                float c = 0.7978845608028654f * (u + 0.044715f * u * u * u);
                float g = 0.5f * u * (1.0f + tanhf(c));
                G[(long)row * FCN + col] = f2b(g);
            }
    }
}

// Residual GEMM with split-K: X += A@W^T (+bias on kz==0), fp32 atomics.
__global__ __launch_bounds__(256) void k_res128(
        const unsigned short* __restrict__ A, int lda,
        const unsigned short* __restrict__ B, int K, int ksplit,
        const float* __restrict__ bias, float* __restrict__ X)
{
    f32x4 acc[4][4];
#pragma unroll
    for (int i = 0; i < 4; ++i)
#pragma unroll
        for (int j = 0; j < 4; ++j) acc[i][j] = 0.f;
    const int m0 = blockIdx.x * 128, n0 = blockIdx.y * 128;
    const int kz = blockIdx.z;
    const int klen = K / ksplit;
    gemm128(A, lda, B, K, m0, n0, kz * klen, kz * klen + klen, acc);
    const int wave = threadIdx.x >> 6, lane = threadIdx.x & 63;
    const int quad = lane >> 4, l16 = lane & 15;
    const int wm = (wave & 1) * 64, wn = (wave >> 1) * 64;
#pragma unroll
    for (int j = 0; j < 4; ++j) {
        int col = n0 + wn + j * 16 + l16;
        float bv = (kz == 0) ? bias[col] : 0.f;
#pragma unroll
        for (int i = 0; i < 4; ++i)
#pragma unroll
            for (int r = 0; r < 4; ++r) {
                int row = m0 + wm + i * 16 + quad * 4 + r;
                atomicAdd(&X[(long)row * CN + col], acc[i][j][r] + bv);
            }
    }
}

// ---------------- fused flash attention ----------------
// One q-block (128 rows at bm*128) of flash attention; 4 waves, each owns 32
// q-rows. KV tiles of 64. Online softmax in MFMA C-layout (row = quad*4+r,
// same mapping for S and Y accumulators -> rescale needs no cross-lane).
// Row reduce = shfl_xor 1,2,4,8 (quad-preserving 16-lane groups). P goes to
// PV A-frag layout via a padded per-wave LDS buffer (stride 70 shorts).
// K/V/Q LDS tiles are [rows][64] with slot XOR-swizzle (slot ^= row&7),
// applied on the pre-swizzled GLOBAL source (global_load_lds dest is linear)
// and on the ds_read side — breaks the 16-way conflict of stride-128B rows.
__device__ __forceinline__ void flash_qblock(
        int bm,
        const unsigned short* __restrict__ qg, const unsigned short* __restrict__ kg,
        const unsigned short* __restrict__ vg, unsigned short* __restrict__ yb,
        unsigned short* Qs, unsigned short* Ks, unsigned short* Vs,
        unsigned short* Ps)
{
    const int tid  = threadIdx.x;
    const int wave = tid >> 6;
    const int lane = tid & 63;
    const int quad = lane >> 4;
    const int l16  = lane & 15;
    const int r8 = lane >> 3;          // row within an 8-row chunk (1KB)
    const int sl = lane & 7;           // 16B slot within a 128B row

    __syncthreads();                   // WAR vs previous q-block's LDS reads

    // ---- stage Q [128][64]: LDS[row][s] = Q[row][s ^ (row&7)] ----
#pragma unroll
    for (int c = 0; c < 4; ++c) {
        int chunk = wave * 4 + c;
        int row = chunk * 8 + r8;
        int slot = sl ^ (row & 7);
        __builtin_amdgcn_global_load_lds(
            (gas_t)(qg + (long)(bm * 128 + row) * 64 + slot * 8),
            (las_t)(Qs + chunk * 512), 16, 0, 0);
    }
    __syncthreads();

    // Q fragments in registers for the whole KV loop (wave-local rows)
    short8 qf[2][2];
#pragma unroll
    for (int i = 0; i < 2; ++i)
#pragma unroll
        for (int ks = 0; ks < 2; ++ks) {
            int row = wave * 32 + i * 16 + l16;
            int slot = (ks * 4 + quad) ^ (row & 7);
            qf[i][ks] = *(const short8*)(Qs + row * 64 + slot * 8);
        }

    f32x4 acc[2][4];
#pragma unroll
    for (int i = 0; i < 2; ++i)
#pragma unroll
        for (int j = 0; j < 4; ++j) acc[i][j] = 0.f;
    float m_run[2][4], l_run[2][4];
#pragma unroll
    for (int i = 0; i < 2; ++i)
#pragma unroll
        for (int r = 0; r < 4; ++r) { m_run[i][r] = -3e38f; l_run[i][r] = 0.f; }

    const int qbase = bm * 128 + wave * 32;
    const int nt = 2 * bm + 2;                 // causal: tiles k0=0..(bm*128+64)
    unsigned short* pw = Ps + wave * (32 * 70);

    for (int t = 0; t < nt; ++t) {
        const int k0 = t * 64;
        __syncthreads();                       // WAR on Ks/Vs
#pragma unroll
        for (int c = 0; c < 2; ++c) {
            int chunk = wave * 2 + c;
            int row = chunk * 8 + r8;
            int slot = sl ^ (row & 7);
            __builtin_amdgcn_global_load_lds(
                (gas_t)(kg + (long)(k0 + row) * 64 + slot * 8),
                (las_t)(Ks + chunk * 512), 16, 0, 0);
            __builtin_amdgcn_global_load_lds(
                (gas_t)(vg + (long)row * TN + k0 + slot * 8),
                (las_t)(Vs + chunk * 512), 16, 0, 0);
        }
        __syncthreads();                       // RAW (vmcnt(0) drain at barrier)

        // S = Q K^T  (A=Q rows q, B=K rows k, kd=d)
        f32x4 s[2][4];
#pragma unroll
        for (int i = 0; i < 2; ++i)
#pragma unroll
            for (int j = 0; j < 4; ++j) s[i][j] = 0.f;
#pragma unroll
        for (int j = 0; j < 4; ++j) {
            int row = j * 16 + l16;
#pragma unroll
            for (int ks = 0; ks < 2; ++ks) {
                int slot = (ks * 4 + quad) ^ (row & 7);
                short8 kf = *(const short8*)(Ks + row * 64 + slot * 8);
#pragma unroll
                for (int i = 0; i < 2; ++i)
                    s[i][j] = __builtin_amdgcn_mfma_f32_16x16x32_bf16(qf[i][ks], kf, s[i][j], 0, 0, 0);
            }
        }

        // online softmax per q-row (i,r). C-layout row = qbase+i*16+quad*4+r.
#pragma unroll
        for (int i = 0; i < 2; ++i) {
#pragma unroll
            for (int r = 0; r < 4; ++r) {
                const int qrow = qbase + i * 16 + quad * 4 + r;
                float mx = -3e38f;
#pragma unroll
                for (int j = 0; j < 4; ++j) {
                    float v = s[i][j][r] * 0.125f;
                    if (k0 + j * 16 + l16 > qrow) v = -3e38f;   // causal mask
                    s[i][j][r] = v;
                    mx = fmaxf(mx, v);
                }
#pragma unroll
                for (int o = 1; o < 16; o <<= 1) mx = fmaxf(mx, __shfl_xor(mx, o));
                const float mnew = fmaxf(m_run[i][r], mx);
                const float resc = __expf(m_run[i][r] - mnew);  // 0 on first tile
                m_run[i][r] = mnew;
                float ls = 0.f;
#pragma unroll
                for (int j = 0; j < 4; ++j) {
                    float p = __expf(s[i][j][r] - mnew);
                    s[i][j][r] = p;
                    ls += p;
                }
#pragma unroll
                for (int o = 1; o < 16; o <<= 1) ls += __shfl_xor(ls, o);
                l_run[i][r] = l_run[i][r] * resc + ls;
#pragma unroll
                for (int j = 0; j < 4; ++j)
                    acc[i][j][r] *= resc;       // same row mapping as S: no shfl
            }
        }

        // P -> per-wave LDS (bf16), C-layout write / A-frag read
#pragma unroll
        for (int i = 0; i < 2; ++i)
#pragma unroll
            for (int j = 0; j < 4; ++j)
#pragma unroll
                for (int r = 0; r < 4; ++r)
                    pw[(i * 16 + quad * 4 + r) * 70 + j * 16 + l16] = f2b(s[i][j][r]);
        __syncthreads();                       // orders P write->read (lgkm drain)

        short8 pa[2][2];
#pragma unroll
        for (int i = 0; i < 2; ++i)
#pragma unroll
            for (int ks = 0; ks < 2; ++ks)
                pa[i][ks] = *(const short8*)(pw + (i * 16 + l16) * 70 + ks * 32 + quad * 8);

        // Y += P V   (A=P rows q kd=k, B=V^T rows d kd=k from vt layout)
#pragma unroll
        for (int j = 0; j < 4; ++j) {
            int row = j * 16 + l16;
#pragma unroll
            for (int ks = 0; ks < 2; ++ks) {
                int slot = (ks * 4 + quad) ^ (row & 7);
                short8 vf = *(const short8*)(Vs + row * 64 + slot * 8);
#pragma unroll
                for (int i = 0; i < 2; ++i)
                    acc[i][j] = __builtin_amdgcn_mfma_f32_16x16x32_bf16(pa[i][ks], vf, acc[i][j], 0, 0, 0);
            }
        }
    }

    // epilogue: Y = acc / l, write [B,T,C] at col h*64
#pragma unroll
    for (int i = 0; i < 2; ++i)
#pragma unroll
        for (int r = 0; r < 4; ++r) {
            const float inv = 1.0f / l_run[i][r];
            const int row = qbase + i * 16 + quad * 4 + r;
#pragma unroll
            for (int j = 0; j < 4; ++j)
                yb[(long)row * CN + j * 16 + l16] = f2b(acc[i][j][r] * inv);
        }
}

// grid (TN/256, 1, BN*HN): each block does q-blocks bm=x and bm=7-x
// (complementary pair -> uniform 18 KV-tiles per block regardless of x;
// fixes the 2.4x tail from same-cost blocks co-resident on one CU).
__global__ __launch_bounds__(256) void k_attn(
        const unsigned short* __restrict__ qb, const unsigned short* __restrict__ kb,
        const unsigned short* __restrict__ vt, unsigned short* __restrict__ y)
{
    __shared__ __align__(16) unsigned short Qs[128 * 64];
    __shared__ __align__(16) unsigned short Ks[64 * 64];
    __shared__ __align__(16) unsigned short Vs[64 * 64];
    __shared__ __align__(16) unsigned short Ps[4 * 32 * 70];

    const int x = blockIdx.x;
    const int z = blockIdx.z;
    const unsigned short* qg = qb + (long)z * TN * 64;
    const unsigned short* kg = kb + (long)z * TN * 64;
    const unsigned short* vg = vt + (long)z * 64 * TN;
    const int b = z / HN, h = z - b * HN;
    unsigned short* yb = y + (long)b * TN * CN + h * 64;

    flash_qblock(x,     qg, kg, vg, yb, Qs, Ks, Vs, Ps);
    flash_qblock(7 - x, qg, kg, vg, yb, Qs, Ks, Vs, Ps);
}

// ---------------- small kernels ----------------
// LayerNorm, wave-per-row (4 rows per block), barrier-free shuffle reduce.
__global__ __launch_bounds__(256) void k_ln(
        const float* __restrict__ X, const float* __restrict__ w,
        const float* __restrict__ b, unsigned short* __restrict__ O)
{
    const int row  = blockIdx.x * 4 + (threadIdx.x >> 6);
    const int lane = threadIdx.x & 63;
    const f32x4* xr = (const f32x4*)(X + (long)row * CN);
    const f32x4* wv = (const f32x4*)w;
    const f32x4* bv = (const f32x4*)b;
    f32x4 v[3];
    float s = 0.f, sq = 0.f;
#pragma unroll
    for (int i = 0; i < 3; ++i) {
        v[i] = xr[i * 64 + lane];
#pragma unroll
        for (int c = 0; c < 4; ++c) { s += v[i][c]; sq += v[i][c] * v[i][c]; }
    }
#pragma unroll
    for (int o = 32; o > 0; o >>= 1) { s += __shfl_xor(s, o); sq += __shfl_xor(sq, o); }
    const float mu = s * (1.0f / CN);
    const float rstd = rsqrtf(sq * (1.0f / CN) - mu * mu + 1e-5f);
    u16x4* orow = (u16x4*)(O + (long)row * CN);
#pragma unroll
    for (int i = 0; i < 3; ++i) {
        f32x4 wc = wv[i * 64 + lane], bc = bv[i * 64 + lane];
        u16x4 o4;
#pragma unroll
        for (int c = 0; c < 4; ++c) o4[c] = f2b((v[i][c] - mu) * rstd * wc[c] + bc[c]);
        orow[i * 64 + lane] = o4;
    }
}

// final LN + head dot (w_head [768,1]) -> out[row] fp32; wave-per-row.
__global__ __launch_bounds__(256) void k_final(
        const float* __restrict__ X, const float* __restrict__ w,
        const float* __restrict__ b, const float* __restrict__ wh,
        float* __restrict__ out)
{
    const int row  = blockIdx.x * 4 + (threadIdx.x >> 6);
    const int lane = threadIdx.x & 63;
    const f32x4* xr = (const f32x4*)(X + (long)row * CN);
    const f32x4* wv = (const f32x4*)w;
    const f32x4* bv = (const f32x4*)b;
    const f32x4* hv = (const f32x4*)wh;
    f32x4 v[3];
    float s = 0.f, sq = 0.f;
#pragma unroll
    for (int i = 0; i < 3; ++i) {
        v[i] = xr[i * 64 + lane];
#pragma unroll
        for (int c = 0; c < 4; ++c) { s += v[i][c]; sq += v[i][c] * v[i][c]; }
    }
#pragma unroll
    for (int o = 32; o > 0; o >>= 1) { s += __shfl_xor(s, o); sq += __shfl_xor(sq, o); }
    const float mu = s * (1.0f / CN);
    const float rstd = rsqrtf(sq * (1.0f / CN) - mu * mu + 1e-5f);
    float acc = 0.f;
#pragma unroll
    for (int i = 0; i < 3; ++i) {
        f32x4 wc = wv[i * 64 + lane], bc = bv[i * 64 + lane], hc = hv[i * 64 + lane];
#pragma unroll
        for (int c = 0; c < 4; ++c)
            acc += ((v[i][c] - mu) * rstd * wc[c] + bc[c]) * hc[c];
    }
#pragma unroll
    for (int o = 32; o > 0; o >>= 1) acc += __shfl_xor(acc, o);
    if (lane == 0) out[row] = acc;
}

// x = wte[idx] + wpe  (f32x4 vectorized)
__global__ __launch_bounds__(256) void k_embed(
        const int* __restrict__ idx, const float* __restrict__ wte,
        const float* __restrict__ wpe, float* __restrict__ X)
{
    long i4 = (long)blockIdx.x * 256 + threadIdx.x;   // group of 4 floats
    int c4 = (int)(i4 % (CN / 4));
    int bt = (int)(i4 / (CN / 4));
    int t = bt & 1023;
    int tok = idx[bt];
    f32x4 a = *(const f32x4*)(wte + (long)tok * CN + c4 * 4);
    f32x4 p = *(const f32x4*)(wpe + (long)t * CN + c4 * 4);
    *(f32x4*)(X + (long)bt * CN + c4 * 4) = a + p;
}

// fp32 [K,N] -> bf16 [N,K] (per layer z), 32x32 LDS tile
__global__ __launch_bounds__(256) void k_transpose(
        const float* __restrict__ in, unsigned short* __restrict__ out, int K, int N)
{
    __shared__ float tile[32][33];
    const int z = blockIdx.z;
    in  += (long)z * K * N;
    out += (long)z * K * N;
    const int n0 = blockIdx.x * 32, k0 = blockIdx.y * 32;
    const int tx = threadIdx.x & 31, ty = threadIdx.x >> 5;
#pragma unroll
    for (int i = 0; i < 4; ++i)
        tile[ty + i * 8][tx] = in[(long)(k0 + ty + i * 8) * N + n0 + tx];
    __syncthreads();
#pragma unroll
    for (int i = 0; i < 4; ++i)
        out[(long)(n0 + ty + i * 8) * K + k0 + tx] = f2b(tile[tx][ty + i * 8]);
}

// ---------------- host ----------------
extern "C" void kernel_launch(void* const* d_in, const int* in_sizes, int n_in,
                              void* d_out, int out_size, void* d_ws, size_t ws_size,
                              hipStream_t stream)
{
    const int*   idx    = (const int*)  d_in[0];
    const float* wte    = (const float*)d_in[1];
    const float* wpe    = (const float*)d_in[2];
    const float* ln1_w  = (const float*)d_in[3];
    const float* ln1_b  = (const float*)d_in[4];
    const float* w_qkv  = (const float*)d_in[5];
    const float* b_qkv  = (const float*)d_in[6];
    const float* w_ao   = (const float*)d_in[7];
    const float* b_ao   = (const float*)d_in[8];
    const float* ln2_w  = (const float*)d_in[9];
    const float* ln2_b  = (const float*)d_in[10];
    const float* w_fc   = (const float*)d_in[11];
    const float* b_fc   = (const float*)d_in[12];
    const float* w_fp   = (const float*)d_in[13];
    const float* b_fp   = (const float*)d_in[14];
    const float* lnf_w  = (const float*)d_in[15];
    const float* lnf_b  = (const float*)d_in[16];
    const float* w_head = (const float*)d_in[17];
    float* out = (float*)d_out;

    char* ws = (char*)d_ws;
    unsigned short* wqkvT = (unsigned short*)(ws + 0L);
    unsigned short* waoT  = (unsigned short*)(ws + 42467328L);
    unsigned short* wfcT  = (unsigned short*)(ws + 56623104L);
    unsigned short* wfpT  = (unsigned short*)(ws + 113246208L);
    float*          x     = (float*)         (ws + 169869312L);
    unsigned short* hb    = (unsigned short*)(ws + 182452224L);
    unsigned short* qb    = (unsigned short*)(ws + 188743680L);
    unsigned short* kb    = (unsigned short*)(ws + 195035136L);
    unsigned short* vt    = (unsigned short*)(ws + 201326592L);
    unsigned short* y     = (unsigned short*)(ws + 308281344L);
    unsigned short* g     = (unsigned short*)(ws + 314572800L);

    hipLaunchKernelGGL(k_transpose, dim3(NKV / 32, CN / 32, NL), dim3(256), 0, stream,
                       w_qkv, wqkvT, CN, NKV);
    hipLaunchKernelGGL(k_transpose, dim3(CN / 32, CN / 32, NL), dim3(256), 0, stream,
                       w_ao, waoT, CN, CN);
    hipLaunchKernelGGL(k_transpose, dim3(FCN / 32, CN / 32, NL), dim3(256), 0, stream,
                       w_fc, wfcT, CN, FCN);
    hipLaunchKernelGGL(k_transpose, dim3(CN / 32, FCN / 32, NL), dim3(256), 0, stream,
                       w_fp, wfpT, FCN, CN);

    hipLaunchKernelGGL(k_embed, dim3(MTOT * (CN / 4) / 256), dim3(256), 0, stream,
                       idx, wte, wpe, x);

    for (int l = 0; l < NL; ++l) {
        hipLaunchKernelGGL(k_ln, dim3(MTOT / 4), dim3(256), 0, stream,
                           x, ln1_w + l * CN, ln1_b + l * CN, hb);
        hipLaunchKernelGGL(k_qkv128, dim3(MTOT / 128, NKV / 128), dim3(256), 0, stream,
                           hb, wqkvT + (long)l * NKV * CN, b_qkv + l * NKV, qb, kb, vt);
        hipLaunchKernelGGL(k_attn, dim3(TN / 256, 1, BN * HN), dim3(256), 0, stream,
                           qb, kb, vt, y);
        hipLaunchKernelGGL(k_res128, dim3(MTOT / 128, CN / 128, 2), dim3(256), 0, stream,
                           y, CN, waoT + (long)l * CN * CN, CN, 2, b_ao + l * CN, x);
        hipLaunchKernelGGL(k_ln, dim3(MTOT / 4), dim3(256), 0, stream,
                           x, ln2_w + l * CN, ln2_b + l * CN, hb);
        hipLaunchKernelGGL(k_fc128, dim3(MTOT / 128, FCN / 128), dim3(256), 0, stream,
                           hb, wfcT + (long)l * FCN * CN, b_fc + l * FCN, g);
        hipLaunchKernelGGL(k_res128, dim3(MTOT / 128, CN / 128, 4), dim3(256), 0, stream,
                           g, FCN, wfpT + (long)l * FCN * CN, FCN, 4, b_fp + l * CN, x);
    }

    hipLaunchKernelGGL(k_final, dim3(MTOT / 4), dim3(256), 0, stream,
                       x, lnf_w, lnf_b, w_head, out);
}

// Round 5
// 2945.154 us; speedup vs baseline: 1.3158x; 1.0998x over previous
//
#include <hip/hip_runtime.h>

// GPT-2 small forward on MI355X. bf16 MFMA GEMMs (fp32 accum), fp32 residual
// stream + LayerNorms. Dense GEMMs use m97-style 128x128 tiles with
// global_load_lds width-16 staging. Attention is a fused flash kernel
// (QK^T -> online softmax -> PV, S never materialized), with complementary
// q-block pairing (bm, 7-bm) per workgroup for deterministic load balance.
// Residual GEMMs write split-K partials (no atomics); the following LN
// kernel fuses x += sum(partials) + bias with the normalization pass.

#define CN    768
#define NKV   2304
#define FCN   3072
#define TN    1024
#define BN    4
#define HN    12
#define NL    12
#define MTOT  4096   // B*T

typedef __attribute__((ext_vector_type(4))) float f32x4;
typedef __attribute__((ext_vector_type(8))) short short8;
typedef __attribute__((ext_vector_type(4))) unsigned short u16x4;

typedef const __attribute__((address_space(1))) void* gas_t;
typedef __attribute__((address_space(3))) void* las_t;

__device__ __forceinline__ unsigned short f2b(float f) {
    unsigned int u = __float_as_uint(f);
    u += 0x7fffu + ((u >> 16) & 1u);          // RNE
    return (unsigned short)(u >> 16);
}
__device__ __forceinline__ float b2f(unsigned short h) {
    return __uint_as_float(((unsigned int)h) << 16);
}

// ---------------- 128x128 bf16 MFMA core (BK=32, global_load_lds) ----------
// A [M,K] bf16 row-major lda; B [N,K] bf16 row-major ldb (i.e. W^T layout).
// 256 threads = 4 waves in 2x2; wave covers 64x64 via 4x4 16x16x32 frags.
// LDS unpadded [128][32] (required: global_load_lds dest = wave base+lane*16).
__device__ __forceinline__ void gemm128(
        const unsigned short* __restrict__ A, int lda,
        const unsigned short* __restrict__ B, int ldb,
        int m0, int n0, int kbeg, int kend, f32x4 acc[4][4])
{
    __shared__ __align__(16) unsigned short As[128 * 32];
    __shared__ __align__(16) unsigned short Bs[128 * 32];
    const int tid  = threadIdx.x;
    const int wave = tid >> 6;
    const int lane = tid & 63;
    const int quad = lane >> 4;
    const int l16  = lane & 15;
    const int wm   = (wave & 1) * 64;
    const int wn   = (wave >> 1) * 64;
    // staging: chunk it in {0,1}: row = it*64 + wave*16 + lane/4, col8=(lane&3)*8
    const int srow = wave * 16 + (lane >> 2);
    const int scol = (lane & 3) << 3;
    const unsigned short* ag = A + (long)(m0 + srow) * lda + scol;
    const unsigned short* bg = B + (long)(n0 + srow) * ldb + scol;
    unsigned short* asw = As + wave * 512;      // +lane*8 implicit in HW
    unsigned short* bsw = Bs + wave * 512;

    for (int k0 = kbeg; k0 < kend; k0 += 32) {
        __syncthreads();                        // WAR vs prior frag reads
        __builtin_amdgcn_global_load_lds((gas_t)(ag + k0),                  (las_t)(asw),            16, 0, 0);
        __builtin_amdgcn_global_load_lds((gas_t)(ag + k0 + (long)64 * lda), (las_t)(asw + 64 * 32),  16, 0, 0);
        __builtin_amdgcn_global_load_lds((gas_t)(bg + k0),                  (las_t)(bsw),            16, 0, 0);
        __builtin_amdgcn_global_load_lds((gas_t)(bg + k0 + (long)64 * ldb), (las_t)(bsw + 64 * 32),  16, 0, 0);
        __syncthreads();                        // compiler adds vmcnt(0) drain
        short8 af[4], bf[4];
#pragma unroll
        for (int i = 0; i < 4; ++i)
            af[i] = *(const short8*)(As + (wm + i * 16 + l16) * 32 + quad * 8);
#pragma unroll
        for (int j = 0; j < 4; ++j)
            bf[j] = *(const short8*)(Bs + (wn + j * 16 + l16) * 32 + quad * 8);
#pragma unroll
        for (int i = 0; i < 4; ++i)
#pragma unroll
            for (int j = 0; j < 4; ++j)
                acc[i][j] = __builtin_amdgcn_mfma_f32_16x16x32_bf16(af[i], bf[j], acc[i][j], 0, 0, 0);
    }
}
// C/D: value r of acc[i][j] -> row = m0+wm+i*16+quad*4+r, col = n0+wn+j*16+l16.

// ---------------- GEMM kernels ----------------
// QKV: [4096,768] @ W^T[2304,768] + bias -> split q/k [B,H,T,D], vT [B,H,D,T]
__global__ __launch_bounds__(256) void k_qkv128(
        const unsigned short* __restrict__ A, const unsigned short* __restrict__ B,
        const float* __restrict__ bias,
        unsigned short* __restrict__ qb, unsigned short* __restrict__ kb,
        unsigned short* __restrict__ vt)
{
    f32x4 acc[4][4];
#pragma unroll
    for (int i = 0; i < 4; ++i)
#pragma unroll
        for (int j = 0; j < 4; ++j) acc[i][j] = 0.f;
    const int m0 = blockIdx.x * 128, n0 = blockIdx.y * 128;
    gemm128(A, CN, B, CN, m0, n0, 0, CN, acc);
    const int wave = threadIdx.x >> 6, lane = threadIdx.x & 63;
    const int quad = lane >> 4, l16 = lane & 15;
    const int wm = (wave & 1) * 64, wn = (wave >> 1) * 64;
#pragma unroll
    for (int j = 0; j < 4; ++j) {
        int col = n0 + wn + j * 16 + l16;
        float bv = bias[col];
        int which = col / CN;
        int cc = col - which * CN;
        int h = cc >> 6, d = cc & 63;
#pragma unroll
        for (int i = 0; i < 4; ++i) {
#pragma unroll
            for (int r = 0; r < 4; ++r) {
                int row = m0 + wm + i * 16 + quad * 4 + r;
                int b = row >> 10, t = row & 1023;
                int bh = b * HN + h;
                unsigned short val = f2b(acc[i][j][r] + bv);
                if (which == 0)      qb[(bh * TN + t) * 64 + d] = val;
                else if (which == 1) kb[(bh * TN + t) * 64 + d] = val;
                else                 vt[(bh * 64 + d) * TN + t] = val;
            }
        }
    }
}

// FC: gelu(A@W^T + bias) -> bf16 [4096,3072]
__global__ __launch_bounds__(256) void k_fc128(
        const unsigned short* __restrict__ A, const unsigned short* __restrict__ B,
        const float* __restrict__ bias, unsigned short* __restrict__ G)
{
    f32x4 acc[4][4];
#pragma unroll
    for (int i = 0; i < 4; ++i)
#pragma unroll
        for (int j = 0; j < 4; ++j) acc[i][j] = 0.f;
    const int m0 = blockIdx.x * 128, n0 = blockIdx.y * 128;
    gemm128(A, CN, B, CN, m0, n0, 0, CN, acc);
    const int wave = threadIdx.x >> 6, lane = threadIdx.x & 63;
    const int quad = lane >> 4, l16 = lane & 15;
    const int wm = (wave & 1) * 64, wn = (wave >> 1) * 64;
#pragma unroll
    for (int j = 0; j < 4; ++j) {
        int col = n0 + wn + j * 16 + l16;
        float bv = bias[col];
#pragma unroll
        for (int i = 0; i < 4; ++i)
#pragma unroll
            for (int r = 0; r < 4; ++r) {
                int row = m0 + wm + i * 16 + quad * 4 + r;
                float u = acc[i][j][r] + bv;
                float c = 0.7978845608028654f * (u + 0.044715f * u * u * u);
                float g = 0.5f * u * (1.0f + tanhf(c));
                G[(long)row * FCN + col] = f2b(g);
            }
    }
}

// Residual GEMM with split-K: partial kz writes its slice sum to its own
// fp32 buffer (plain stores, no atomics). Bias is added by the consuming
// fused-LN kernel.
__global__ __launch_bounds__(256) void k_part128(
        const unsigned short* __restrict__ A, int lda,
        const unsigned short* __restrict__ B, int K, int ksplit,
        float* __restrict__ part)
{
    f32x4 acc[4][4];
#pragma unroll
    for (int i = 0; i < 4; ++i)
#pragma unroll
        for (int j = 0; j < 4; ++j) acc[i][j] = 0.f;
    const int m0 = blockIdx.x * 128, n0 = blockIdx.y * 128;
    const int kz = blockIdx.z;
    const int klen = K / ksplit;
    gemm128(A, lda, B, K, m0, n0, kz * klen, kz * klen + klen, acc);
    float* P = part + (long)kz * MTOT * CN;
    const int wave = threadIdx.x >> 6, lane = threadIdx.x & 63;
    const int quad = lane >> 4, l16 = lane & 15;
    const int wm = (wave & 1) * 64, wn = (wave >> 1) * 64;
#pragma unroll
    for (int j = 0; j < 4; ++j) {
        int col = n0 + wn + j * 16 + l16;
#pragma unroll
        for (int i = 0; i < 4; ++i)
#pragma unroll
            for (int r = 0; r < 4; ++r) {
                int row = m0 + wm + i * 16 + quad * 4 + r;
                P[(long)row * CN + col] = acc[i][j][r];
            }
    }
}

// ---------------- fused flash attention ----------------
// One q-block (128 rows at bm*128) of flash attention; 4 waves, each owns 32
// q-rows. KV tiles of 64. Online softmax in MFMA C-layout (row = quad*4+r,
// same mapping for S and Y accumulators -> rescale needs no cross-lane).
// Row reduce = shfl_xor 1,2,4,8 (quad-preserving 16-lane groups). P goes to
// PV A-frag layout via a padded per-wave LDS buffer (stride 70 shorts).
// K/V/Q LDS tiles are [rows][64] with slot XOR-swizzle (slot ^= row&7),
// applied on the pre-swizzled GLOBAL source (global_load_lds dest is linear)
// and on the ds_read side — breaks the 16-way conflict of stride-128B rows.
__device__ __forceinline__ void flash_qblock(
        int bm,
        const unsigned short* __restrict__ qg, const unsigned short* __restrict__ kg,
        const unsigned short* __restrict__ vg, unsigned short* __restrict__ yb,
        unsigned short* Qs, unsigned short* Ks, unsigned short* Vs,
        unsigned short* Ps)
{
    const int tid  = threadIdx.x;
    const int wave = tid >> 6;
    const int lane = tid & 63;
    const int quad = lane >> 4;
    const int l16  = lane & 15;
    const int r8 = lane >> 3;          // row within an 8-row chunk (1KB)
    const int sl = lane & 7;           // 16B slot within a 128B row

    __syncthreads();                   // WAR vs previous q-block's LDS reads

    // ---- stage Q [128][64]: LDS[row][s] = Q[row][s ^ (row&7)] ----
#pragma unroll
    for (int c = 0; c < 4; ++c) {
        int chunk = wave * 4 + c;
        int row = chunk * 8 + r8;
        int slot = sl ^ (row & 7);
        __builtin_amdgcn_global_load_lds(
            (gas_t)(qg + (long)(bm * 128 + row) * 64 + slot * 8),
            (las_t)(Qs + chunk * 512), 16, 0, 0);
    }
    __syncthreads();

    // Q fragments in registers for the whole KV loop (wave-local rows)
    short8 qf[2][2];
#pragma unroll
    for (int i = 0; i < 2; ++i)
#pragma unroll
        for (int ks = 0; ks < 2; ++ks) {
            int row = wave * 32 + i * 16 + l16;
            int slot = (ks * 4 + quad) ^ (row & 7);
            qf[i][ks] = *(const short8*)(Qs + row * 64 + slot * 8);
        }

    f32x4 acc[2][4];
#pragma unroll
    for (int i = 0; i < 2; ++i)
#pragma unroll
        for (int j = 0; j < 4; ++j) acc[i][j] = 0.f;
    float m_run[2][4], l_run[2][4];
#pragma unroll
    for (int i = 0; i < 2; ++i)
#pragma unroll
        for (int r = 0; r < 4; ++r) { m_run[i][r] = -3e38f; l_run[i][r] = 0.f; }

    const int qbase = bm * 128 + wave * 32;
    const int nt = 2 * bm + 2;                 // causal: tiles k0=0..(bm*128+64)
    unsigned short* pw = Ps + wave * (32 * 70);

    for (int t = 0; t < nt; ++t) {
        const int k0 = t * 64;
        __syncthreads();                       // WAR on Ks/Vs
#pragma unroll
        for (int c = 0; c < 2; ++c) {
            int chunk = wave * 2 + c;
            int row = chunk * 8 + r8;
            int slot = sl ^ (row & 7);
            __builtin_amdgcn_global_load_lds(
                (gas_t)(kg + (long)(k0 + row) * 64 + slot * 8),
                (las_t)(Ks + chunk * 512), 16, 0, 0);
            __builtin_amdgcn_global_load_lds(
                (gas_t)(vg + (long)row * TN + k0 + slot * 8),
                (las_t)(Vs + chunk * 512), 16, 0, 0);
        }
        __syncthreads();                       // RAW (vmcnt(0) drain at barrier)

        // S = Q K^T  (A=Q rows q, B=K rows k, kd=d)
        f32x4 s[2][4];
#pragma unroll
        for (int i = 0; i < 2; ++i)
#pragma unroll
            for (int j = 0; j < 4; ++j) s[i][j] = 0.f;
#pragma unroll
        for (int j = 0; j < 4; ++j) {
            int row = j * 16 + l16;
#pragma unroll
            for (int ks = 0; ks < 2; ++ks) {
                int slot = (ks * 4 + quad) ^ (row & 7);
                short8 kf = *(const short8*)(Ks + row * 64 + slot * 8);
#pragma unroll
                for (int i = 0; i < 2; ++i)
                    s[i][j] = __builtin_amdgcn_mfma_f32_16x16x32_bf16(qf[i][ks], kf, s[i][j], 0, 0, 0);
            }
        }

        // online softmax per q-row (i,r). C-layout row = qbase+i*16+quad*4+r.
#pragma unroll
        for (int i = 0; i < 2; ++i) {
#pragma unroll
            for (int r = 0; r < 4; ++r) {
                const int qrow = qbase + i * 16 + quad * 4 + r;
                float mx = -3e38f;
#pragma unroll
                for (int j = 0; j < 4; ++j) {
                    float v = s[i][j][r] * 0.125f;
                    if (k0 + j * 16 + l16 > qrow) v = -3e38f;   // causal mask
                    s[i][j][r] = v;
                    mx = fmaxf(mx, v);
                }
#pragma unroll
                for (int o = 1; o < 16; o <<= 1) mx = fmaxf(mx, __shfl_xor(mx, o));
                const float mnew = fmaxf(m_run[i][r], mx);
                const float resc = __expf(m_run[i][r] - mnew);  // 0 on first tile
                m_run[i][r] = mnew;
                float ls = 0.f;
#pragma unroll
                for (int j = 0; j < 4; ++j) {
                    float p = __expf(s[i][j][r] - mnew);
                    s[i][j][r] = p;
                    ls += p;
                }
#pragma unroll
                for (int o = 1; o < 16; o <<= 1) ls += __shfl_xor(ls, o);
                l_run[i][r] = l_run[i][r] * resc + ls;
#pragma unroll
                for (int j = 0; j < 4; ++j)
                    acc[i][j][r] *= resc;       // same row mapping as S: no shfl
            }
        }

        // P -> per-wave LDS (bf16), C-layout write / A-frag read
#pragma unroll
        for (int i = 0; i < 2; ++i)
#pragma unroll
            for (int j = 0; j < 4; ++j)
#pragma unroll
                for (int r = 0; r < 4; ++r)
                    pw[(i * 16 + quad * 4 + r) * 70 + j * 16 + l16] = f2b(s[i][j][r]);
        __syncthreads();                       // orders P write->read (lgkm drain)

        short8 pa[2][2];
#pragma unroll
        for (int i = 0; i < 2; ++i)
#pragma unroll
            for (int ks = 0; ks < 2; ++ks)
                pa[i][ks] = *(const short8*)(pw + (i * 16 + l16) * 70 + ks * 32 + quad * 8);

        // Y += P V   (A=P rows q kd=k, B=V^T rows d kd=k from vt layout)
#pragma unroll
        for (int j = 0; j < 4; ++j) {
            int row = j * 16 + l16;
#pragma unroll
            for (int ks = 0; ks < 2; ++ks) {
                int slot = (ks * 4 + quad) ^ (row & 7);
                short8 vf = *(const short8*)(Vs + row * 64 + slot * 8);
#pragma unroll
                for (int i = 0; i < 2; ++i)
                    acc[i][j] = __builtin_amdgcn_mfma_f32_16x16x32_bf16(pa[i][ks], vf, acc[i][j], 0, 0, 0);
            }
        }
    }

    // epilogue: Y = acc / l, write [B,T,C] at col h*64
#pragma unroll
    for (int i = 0; i < 2; ++i)
#pragma unroll
        for (int r = 0; r < 4; ++r) {
            const float inv = 1.0f / l_run[i][r];
            const int row = qbase + i * 16 + quad * 4 + r;
#pragma unroll
            for (int j = 0; j < 4; ++j)
                yb[(long)row * CN + j * 16 + l16] = f2b(acc[i][j][r] * inv);
        }
}

// grid (TN/256, 1, BN*HN): each block does q-blocks bm=x and bm=7-x
// (complementary pair -> uniform 18 KV-tiles per block regardless of x;
// fixes the 2.4x tail from same-cost blocks co-resident on one CU).
__global__ __launch_bounds__(256) void k_attn(
        const unsigned short* __restrict__ qb, const unsigned short* __restrict__ kb,
        const unsigned short* __restrict__ vt, unsigned short* __restrict__ y)
{
    __shared__ __align__(16) unsigned short Qs[128 * 64];
    __shared__ __align__(16) unsigned short Ks[64 * 64];
    __shared__ __align__(16) unsigned short Vs[64 * 64];
    __shared__ __align__(16) unsigned short Ps[4 * 32 * 70];

    const int x = blockIdx.x;
    const int z = blockIdx.z;
    const unsigned short* qg = qb + (long)z * TN * 64;
    const unsigned short* kg = kb + (long)z * TN * 64;
    const unsigned short* vg = vt + (long)z * 64 * TN;
    const int b = z / HN, h = z - b * HN;
    unsigned short* yb = y + (long)b * TN * CN + h * 64;

    flash_qblock(x,     qg, kg, vg, yb, Qs, Ks, Vs, Ps);
    flash_qblock(7 - x, qg, kg, vg, yb, Qs, Ks, Vs, Ps);
}

// ---------------- small kernels ----------------
// Fused residual-reduce + LayerNorm, wave-per-row (4 rows/block), barrier-free.
// nparts>0: x += sum(part[p]) + bias (writes x back), then LN(x) -> O.
__global__ __launch_bounds__(256) void k_lnr(
        float* __restrict__ X, const float* __restrict__ part, int nparts,
        const float* __restrict__ bias,
        const float* __restrict__ w, const float* __restrict__ b,
        unsigned short* __restrict__ O)
{
    const int row  = blockIdx.x * 4 + (threadIdx.x >> 6);
    const int lane = threadIdx.x & 63;
    f32x4* xr = (f32x4*)(X + (long)row * CN);
    const f32x4* wv = (const f32x4*)w;
    const f32x4* bv = (const f32x4*)b;
    f32x4 v[3];
#pragma unroll
    for (int i = 0; i < 3; ++i) v[i] = xr[i * 64 + lane];
    if (nparts > 0) {
        const f32x4* bb = (const f32x4*)bias;
#pragma unroll
        for (int i = 0; i < 3; ++i) v[i] += bb[i * 64 + lane];
        for (int p = 0; p < nparts; ++p) {
            const f32x4* pr = (const f32x4*)(part + (long)p * MTOT * CN + (long)row * CN);
#pragma unroll
            for (int i = 0; i < 3; ++i) v[i] += pr[i * 64 + lane];
        }
#pragma unroll
        for (int i = 0; i < 3; ++i) xr[i * 64 + lane] = v[i];
    }
    float s = 0.f, sq = 0.f;
#pragma unroll
    for (int i = 0; i < 3; ++i)
#pragma unroll
        for (int c = 0; c < 4; ++c) { s += v[i][c]; sq += v[i][c] * v[i][c]; }
#pragma unroll
    for (int o = 32; o > 0; o >>= 1) { s += __shfl_xor(s, o); sq += __shfl_xor(sq, o); }
    const float mu = s * (1.0f / CN);
    const float rstd = rsqrtf(sq * (1.0f / CN) - mu * mu + 1e-5f);
    u16x4* orow = (u16x4*)(O + (long)row * CN);
#pragma unroll
    for (int i = 0; i < 3; ++i) {
        f32x4 wc = wv[i * 64 + lane], bc = bv[i * 64 + lane];
        u16x4 o4;
#pragma unroll
        for (int c = 0; c < 4; ++c) o4[c] = f2b((v[i][c] - mu) * rstd * wc[c] + bc[c]);
        orow[i * 64 + lane] = o4;
    }
}

// final: x + sum(4 partials) + bias -> LN -> dot w_head -> out[row]; wave-per-row.
__global__ __launch_bounds__(256) void k_finalr(
        const float* __restrict__ X, const float* __restrict__ part,
        const float* __restrict__ bias,
        const float* __restrict__ w, const float* __restrict__ b,
        const float* __restrict__ wh, float* __restrict__ out)
{
    const int row  = blockIdx.x * 4 + (threadIdx.x >> 6);
    const int lane = threadIdx.x & 63;
    const f32x4* xr = (const f32x4*)(X + (long)row * CN);
    const f32x4* wv = (const f32x4*)w;
    const f32x4* bv = (const f32x4*)b;
    const f32x4* hv = (const f32x4*)wh;
    const f32x4* bb = (const f32x4*)bias;
    f32x4 v[3];
#pragma unroll
    for (int i = 0; i < 3; ++i) v[i] = xr[i * 64 + lane] + bb[i * 64 + lane];
    for (int p = 0; p < 4; ++p) {
        const f32x4* pr = (const f32x4*)(part + (long)p * MTOT * CN + (long)row * CN);
#pragma unroll
        for (int i = 0; i < 3; ++i) v[i] += pr[i * 64 + lane];
    }
    float s = 0.f, sq = 0.f;
#pragma unroll
    for (int i = 0; i < 3; ++i)
#pragma unroll
        for (int c = 0; c < 4; ++c) { s += v[i][c]; sq += v[i][c] * v[i][c]; }
#pragma unroll
    for (int o = 32; o > 0; o >>= 1) { s += __shfl_xor(s, o); sq += __shfl_xor(sq, o); }
    const float mu = s * (1.0f / CN);
    const float rstd = rsqrtf(sq * (1.0f / CN) - mu * mu + 1e-5f);
    float acc = 0.f;
#pragma unroll
    for (int i = 0; i < 3; ++i) {
        f32x4 wc = wv[i * 64 + lane], bc = bv[i * 64 + lane], hc = hv[i * 64 + lane];
#pragma unroll
        for (int c = 0; c < 4; ++c)
            acc += ((v[i][c] - mu) * rstd * wc[c] + bc[c]) * hc[c];
    }
#pragma unroll
    for (int o = 32; o > 0; o >>= 1) acc += __shfl_xor(acc, o);
    if (lane == 0) out[row] = acc;
}

// x = wte[idx] + wpe  (f32x4 vectorized)
__global__ __launch_bounds__(256) void k_embed(
        const int* __restrict__ idx, const float* __restrict__ wte,
        const float* __restrict__ wpe, float* __restrict__ X)
{
    long i4 = (long)blockIdx.x * 256 + threadIdx.x;   // group of 4 floats
    int c4 = (int)(i4 % (CN / 4));
    int bt = (int)(i4 / (CN / 4));
    int t = bt & 1023;
    int tok = idx[bt];
    f32x4 a = *(const f32x4*)(wte + (long)tok * CN + c4 * 4);
    f32x4 p = *(const f32x4*)(wpe + (long)t * CN + c4 * 4);
    *(f32x4*)(X + (long)bt * CN + c4 * 4) = a + p;
}

// fp32 [K,N] -> bf16 [N,K] (per layer z), 32x32 LDS tile
__global__ __launch_bounds__(256) void k_transpose(
        const float* __restrict__ in, unsigned short* __restrict__ out, int K, int N)
{
    __shared__ float tile[32][33];
    const int z = blockIdx.z;
    in  += (long)z * K * N;
    out += (long)z * K * N;
    const int n0 = blockIdx.x * 32, k0 = blockIdx.y * 32;
    const int tx = threadIdx.x & 31, ty = threadIdx.x >> 5;
#pragma unroll
    for (int i = 0; i < 4; ++i)
        tile[ty + i * 8][tx] = in[(long)(k0 + ty + i * 8) * N + n0 + tx];
    __syncthreads();
#pragma unroll
    for (int i = 0; i < 4; ++i)
        out[(long)(n0 + ty + i * 8) * K + k0 + tx] = f2b(tile[tx][ty + i * 8]);
}

// ---------------- host ----------------
extern "C" void kernel_launch(void* const* d_in, const int* in_sizes, int n_in,
                              void* d_out, int out_size, void* d_ws, size_t ws_size,
                              hipStream_t stream)
{
    const int*   idx    = (const int*)  d_in[0];
    const float* wte    = (const float*)d_in[1];
    const float* wpe    = (const float*)d_in[2];
    const float* ln1_w  = (const float*)d_in[3];
    const float* ln1_b  = (const float*)d_in[4];
    const float* w_qkv  = (const float*)d_in[5];
    const float* b_qkv  = (const float*)d_in[6];
    const float* w_ao   = (const float*)d_in[7];
    const float* b_ao   = (const float*)d_in[8];
    const float* ln2_w  = (const float*)d_in[9];
    const float* ln2_b  = (const float*)d_in[10];
    const float* w_fc   = (const float*)d_in[11];
    const float* b_fc   = (const float*)d_in[12];
    const float* w_fp   = (const float*)d_in[13];
    const float* b_fp   = (const float*)d_in[14];
    const float* lnf_w  = (const float*)d_in[15];
    const float* lnf_b  = (const float*)d_in[16];
    const float* w_head = (const float*)d_in[17];
    float* out = (float*)d_out;

    char* ws = (char*)d_ws;
    unsigned short* wqkvT = (unsigned short*)(ws + 0L);
    unsigned short* waoT  = (unsigned short*)(ws + 42467328L);
    unsigned short* wfcT  = (unsigned short*)(ws + 56623104L);
    unsigned short* wfpT  = (unsigned short*)(ws + 113246208L);
    float*          x     = (float*)         (ws + 169869312L);
    unsigned short* hb    = (unsigned short*)(ws + 182452224L);
    unsigned short* qb    = (unsigned short*)(ws + 188743680L);
    unsigned short* kb    = (unsigned short*)(ws + 195035136L);
    unsigned short* vt    = (unsigned short*)(ws + 201326592L);
    float*          part  = (float*)         (ws + 207618048L);  // 4x 12.6MB (old S slot)
    unsigned short* y     = (unsigned short*)(ws + 308281344L);
    unsigned short* g     = (unsigned short*)(ws + 314572800L);

    hipLaunchKernelGGL(k_transpose, dim3(NKV / 32, CN / 32, NL), dim3(256), 0, stream,
                       w_qkv, wqkvT, CN, NKV);
    hipLaunchKernelGGL(k_transpose, dim3(CN / 32, CN / 32, NL), dim3(256), 0, stream,
                       w_ao, waoT, CN, CN);
    hipLaunchKernelGGL(k_transpose, dim3(FCN / 32, CN / 32, NL), dim3(256), 0, stream,
                       w_fc, wfcT, CN, FCN);
    hipLaunchKernelGGL(k_transpose, dim3(CN / 32, FCN / 32, NL), dim3(256), 0, stream,
                       w_fp, wfpT, FCN, CN);

    hipLaunchKernelGGL(k_embed, dim3(MTOT * (CN / 4) / 256), dim3(256), 0, stream,
                       idx, wte, wpe, x);

    for (int l = 0; l < NL; ++l) {
        // ln1: for l>0 fuse the previous layer's FP residual (4 partials)
        hipLaunchKernelGGL(k_lnr, dim3(MTOT / 4), dim3(256), 0, stream,
                           x, part, (l == 0) ? 0 : 4,
                           (l == 0) ? (const float*)nullptr : (b_fp + (l - 1) * CN),
                           ln1_w + l * CN, ln1_b + l * CN, hb);
        hipLaunchKernelGGL(k_qkv128, dim3(MTOT / 128, NKV / 128), dim3(256), 0, stream,
                           hb, wqkvT + (long)l * NKV * CN, b_qkv + l * NKV, qb, kb, vt);
        hipLaunchKernelGGL(k_attn, dim3(TN / 256, 1, BN * HN), dim3(256), 0, stream,
                           qb, kb, vt, y);
        hipLaunchKernelGGL(k_part128, dim3(MTOT / 128, CN / 128, 2), dim3(256), 0, stream,
                           y, CN, waoT + (long)l * CN * CN, CN, 2, part);
        // ln2: fuse attention-proj residual (2 partials)
        hipLaunchKernelGGL(k_lnr, dim3(MTOT / 4), dim3(256), 0, stream,
                           x, part, 2, b_ao + l * CN,
                           ln2_w + l * CN, ln2_b + l * CN, hb);
        hipLaunchKernelGGL(k_fc128, dim3(MTOT / 128, FCN / 128), dim3(256), 0, stream,
                           hb, wfcT + (long)l * FCN * CN, b_fc + l * FCN, g);
        hipLaunchKernelGGL(k_part128, dim3(MTOT / 128, CN / 128, 4), dim3(256), 0, stream,
                           g, FCN, wfpT + (long)l * FCN * CN, FCN, 4, part);
    }

    hipLaunchKernelGGL(k_finalr, dim3(MTOT / 4), dim3(256), 0, stream,
                       x, part, b_fp + (NL - 1) * CN, lnf_w, lnf_b, w_head, out);
}